// Round 4
// baseline (330.983 us; speedup 1.0000x reference)
//
#include <hip/hip_runtime.h>
#include <stdint.h>

// ---------------------------------------------------------------------------
// EmbraceNet: dock_f = relu(x_f @ W_f + b_f)  (4 modalities, fp32 in)
//             out[b,e] = dock_{idx[b,e]}[b,e]
// idx = jax.random.categorical(key=42, uniform logits), reproduced bit-exactly:
//   * threefry_partitionable (modern JAX default): for 32-bit draws,
//       counts_hi, counts_lo = iota_2x32_shape(shape)      # (0, i) for n<2^32
//       bits1, bits2 = threefry2x32(key=(0,42), (0, i))
//       bits = convert_uint32(bits1 ^ bits2)               # XOR of both words!
//     [R1 eliminated legacy split-halves; R2 eliminated y0 alone; R3
//      eliminated y1 alone; this is y0^y1 per jax/_src/prng.py.]
//   * gumbel = -log(-log(u)) separation between distinct 23-bit mantissas is
//     >=3.7 fp32 ulp, so fp32 gumbel is strictly monotone in the mantissa;
//     argmax over (bits>>9) with strict > (= first-index tie-break) is exact.
// ---------------------------------------------------------------------------

typedef short short8 __attribute__((ext_vector_type(8)));
typedef float floatx4 __attribute__((ext_vector_type(4)));

#define B_DIM 4096
#define K_DIM 1024
#define E_DIM 2048

// fp32 -> bf16 round-to-nearest-even
__device__ __forceinline__ uint16_t f2bf(float x) {
  uint32_t u = __float_as_uint(x);
  u += 0x7FFFu + ((u >> 16) & 1u);
  return (uint16_t)(u >> 16);
}

// JAX threefry2x32, key = (0, 42)
__device__ __forceinline__ void threefry(uint32_t x0, uint32_t x1,
                                         uint32_t& o0, uint32_t& o1) {
  const uint32_t ks0 = 0u;
  const uint32_t ks1 = 42u;
  const uint32_t ks2 = 0x1BD11BDAu ^ 42u;
  x0 += ks0; x1 += ks1;
#define TF_R(r) { x0 += x1; x1 = (x1 << r) | (x1 >> (32 - r)); x1 ^= x0; }
  TF_R(13) TF_R(15) TF_R(26) TF_R(6)
  x0 += ks1; x1 += ks2 + 1u;
  TF_R(17) TF_R(29) TF_R(16) TF_R(24)
  x0 += ks2; x1 += ks0 + 2u;
  TF_R(13) TF_R(15) TF_R(26) TF_R(6)
  x0 += ks0; x1 += ks1 + 3u;
  TF_R(17) TF_R(29) TF_R(16) TF_R(24)
  x0 += ks1; x1 += ks2 + 4u;
  TF_R(13) TF_R(15) TF_R(26) TF_R(6)
  x0 += ks2; x1 += ks0 + 5u;
#undef TF_R
  o0 = x0; o1 = x1;
}

// idxT flat layout [e][b]. Flat gumbel index i = (e*4096+b)*4 + f, n = 2^25.
// Partitionable threefry 32-bit: bits[i] = y0 ^ y1 of threefry((0,42), (0,i)).
__global__ __launch_bounds__(256) void idx_kernel(uint8_t* __restrict__ idxT) {
  uint32_t tid = blockIdx.x * 256u + threadIdx.x;  // e*4096 + b, 0..2^23-1
  uint32_t base = tid << 2;
  uint32_t best = 0, bi = 0;
#pragma unroll
  for (uint32_t f = 0; f < 4; ++f) {
    uint32_t y0, y1;
    threefry(0u, base + f, y0, y1);
    uint32_t m = (y0 ^ y1) >> 9;
    if (f == 0) best = m;
    else if (m > best) { best = m; bi = f; }  // strict > == first-index tiebreak
  }
  idxT[tid] = (uint8_t)bi;
}

// x fp32 [B][K] -> bf16 [f][B][K]
__global__ __launch_bounds__(256) void convert_x(
    const float* __restrict__ x0, const float* __restrict__ x1,
    const float* __restrict__ x2, const float* __restrict__ x3,
    uint16_t* __restrict__ xb) {
  int f = blockIdx.z;
  const float* x = (f == 0) ? x0 : (f == 1) ? x1 : (f == 2) ? x2 : x3;
  size_t i = ((size_t)blockIdx.x * 256 + threadIdx.x) * 4;
  float4 v = *(const float4*)(x + i);
  union { uint16_t h[4]; uint64_t q; } p;
  p.h[0] = f2bf(v.x); p.h[1] = f2bf(v.y);
  p.h[2] = f2bf(v.z); p.h[3] = f2bf(v.w);
  *(uint64_t*)(xb + (size_t)f * B_DIM * K_DIM + i) = p.q;
}

// W fp32 [K][E] -> bf16 Wt [f][E][K]  (transpose via LDS tile)
__global__ __launch_bounds__(256) void convert_w(
    const float* __restrict__ W0, const float* __restrict__ W1,
    const float* __restrict__ W2, const float* __restrict__ W3,
    uint16_t* __restrict__ Wt) {
  __shared__ float tile[32][33];
  int f = blockIdx.z;
  const float* W = (f == 0) ? W0 : (f == 1) ? W1 : (f == 2) ? W2 : W3;
  int e0 = blockIdx.x * 32, k0 = blockIdx.y * 32;
  int tx = threadIdx.x, ty = threadIdx.y;
#pragma unroll
  for (int i = 0; i < 4; ++i)
    tile[ty + i * 8][tx] = W[(size_t)(k0 + ty + i * 8) * E_DIM + e0 + tx];
  __syncthreads();
  uint16_t* dst = Wt + (size_t)f * E_DIM * K_DIM;
#pragma unroll
  for (int i = 0; i < 4; ++i)
    dst[(size_t)(e0 + ty + i * 8) * K_DIM + k0 + tx] = f2bf(tile[tx][ty + i * 8]);
}

__device__ __forceinline__ void async16(const uint16_t* g, uint16_t* lds) {
  __builtin_amdgcn_global_load_lds(
      (const __attribute__((address_space(1))) void*)g,
      (__attribute__((address_space(3))) void*)lds, 16, 0, 0);
}

// m97-style bf16 GEMM, 128x128 tile, BK=32, 4 waves (2x2 of 64x64),
// grid.z = modality f; epilogue: +bias, relu, store only where idx==f.
__global__ __launch_bounds__(256) void gemm_sel(
    const uint16_t* __restrict__ Ab, const uint16_t* __restrict__ Bbt,
    const uint8_t* __restrict__ idxT,
    const float* __restrict__ bias0, const float* __restrict__ bias1,
    const float* __restrict__ bias2, const float* __restrict__ bias3,
    float* __restrict__ out) {
  __shared__ uint16_t As[128 * 32];
  __shared__ uint16_t Bs[128 * 32];

  const int f = blockIdx.z;
  const int tid = threadIdx.x;
  const int w = tid >> 6;        // wave 0..3
  const int l = tid & 63;        // lane
  const int mBase = blockIdx.y * 128;
  const int nBase = blockIdx.x * 128;

  const uint16_t* A = Ab  + (size_t)f * B_DIM * K_DIM + (size_t)mBase * K_DIM;
  const uint16_t* B = Bbt + (size_t)f * E_DIM * K_DIM + (size_t)nBase * K_DIM;

  const int wm = (w >> 1) * 64, wn = (w & 1) * 64;  // wave subtile
  const int ar = l >> 2, ac8 = l & 3;               // staging row/8-col chunk
  const int fr = l & 15, fq = l >> 4;               // fragment row, quad

  floatx4 acc[4][4] = {};

  for (int k0 = 0; k0 < K_DIM; k0 += 32) {
    // stage 128x32 A and B tiles: wave w covers chunks {2w, 2w+1};
    // chunk c = rows [16c,16c+16), lane's 16B lands at LDS c*1024 + lane*16.
    #pragma unroll
    for (int t = 0; t < 2; ++t) {
      int c = w * 2 + t;
      async16(A + (size_t)(c * 16 + ar) * K_DIM + k0 + ac8 * 8, &As[c * 512]);
      async16(B + (size_t)(c * 16 + ar) * K_DIM + k0 + ac8 * 8, &Bs[c * 512]);
    }
    __syncthreads();

    short8 a[4], b[4];
    #pragma unroll
    for (int mi = 0; mi < 4; ++mi)
      a[mi] = *(const short8*)&As[(wm + mi * 16 + fr) * 32 + fq * 8];
    #pragma unroll
    for (int ni = 0; ni < 4; ++ni)
      b[ni] = *(const short8*)&Bs[(wn + ni * 16 + fr) * 32 + fq * 8];
    #pragma unroll
    for (int mi = 0; mi < 4; ++mi)
      #pragma unroll
      for (int ni = 0; ni < 4; ++ni)
        acc[mi][ni] = __builtin_amdgcn_mfma_f32_16x16x32_bf16(
            a[mi], b[ni], acc[mi][ni], 0, 0, 0);
    __syncthreads();
  }

  const float* bias = (f == 0) ? bias0 : (f == 1) ? bias1 : (f == 2) ? bias2 : bias3;
  // C/D layout: col = lane&15, row = (lane>>4)*4 + reg
  #pragma unroll
  for (int ni = 0; ni < 4; ++ni) {
    int col = nBase + wn + ni * 16 + fr;
    float bv = bias[col];
    #pragma unroll
    for (int mi = 0; mi < 4; ++mi) {
      int row0 = mBase + wm + mi * 16 + fq * 4;
      uint32_t iv = *(const uint32_t*)&idxT[(size_t)col * B_DIM + row0];
      floatx4 v = acc[mi][ni];
      #pragma unroll
      for (int r = 0; r < 4; ++r) {
        if (((iv >> (8 * r)) & 255u) == (uint32_t)f) {
          float o = v[r] + bv;
          out[(size_t)(row0 + r) * E_DIM + col] = o > 0.f ? o : 0.f;
        }
      }
    }
  }
}

extern "C" void kernel_launch(void* const* d_in, const int* in_sizes, int n_in,
                              void* d_out, int out_size, void* d_ws, size_t ws_size,
                              hipStream_t stream) {
  const float* x[4]; const float* W[4]; const float* bs[4];
  for (int f = 0; f < 4; ++f) {
    x[f]  = (const float*)d_in[3 * f + 0];
    W[f]  = (const float*)d_in[3 * f + 1];
    bs[f] = (const float*)d_in[3 * f + 2];
  }
  char* ws = (char*)d_ws;
  uint16_t* xb  = (uint16_t*)ws;                                   // 32 MB
  uint16_t* Wt  = (uint16_t*)(ws + (size_t)32 * 1024 * 1024);      // 16 MB
  uint8_t*  idxT = (uint8_t*)(ws + (size_t)48 * 1024 * 1024);      //  8 MB
  float* out = (float*)d_out;

  idx_kernel<<<dim3(32768), dim3(256), 0, stream>>>(idxT);
  convert_x<<<dim3(4096, 1, 4), dim3(256), 0, stream>>>(x[0], x[1], x[2], x[3], xb);
  convert_w<<<dim3(64, 32, 4), dim3(32, 8), 0, stream>>>(W[0], W[1], W[2], W[3], Wt);
  gemm_sel<<<dim3(E_DIM / 128, B_DIM / 128, 4), dim3(256), 0, stream>>>(
      xb, Wt, idxT, bs[0], bs[1], bs[2], bs[3], out);
}

// Round 5
// 312.805 us; speedup vs baseline: 1.0581x; 1.0581x over previous
//
#include <hip/hip_runtime.h>
#include <stdint.h>

// ---------------------------------------------------------------------------
// EmbraceNet fused: out[b,e] = relu(x_f @ W_f + b_f)[b,e],  f = idx[b,e]
// idx = categorical(key=42, uniform): partitionable threefry, bits = y0^y1
// of threefry2x32((0,42), (0, (e*4096+b)*4+f)); argmax over mantissa bits>>9
// (strict > = first-index tie-break; exact — gumbel strictly monotone in
// mantissa, min separation ~3.7 ulp). Verified PASS in R4 (absmax 0.031).
//
// R5 restructure: one block = one 128x128 (b,e) tile, f-loop INSIDE block.
//  - output written once, dense, coalesced (kills R4's 150MB write-amp)
//  - idx computed in-block (2 bits/output packed in 4 VGPRs), no idxT array,
//    no scattered column-major idx reads, one fewer dispatch
// ---------------------------------------------------------------------------

typedef short short8 __attribute__((ext_vector_type(8)));
typedef float floatx4 __attribute__((ext_vector_type(4)));

#define B_DIM 4096
#define K_DIM 1024
#define E_DIM 2048

__device__ __forceinline__ uint16_t f2bf(float x) {
  uint32_t u = __float_as_uint(x);
  u += 0x7FFFu + ((u >> 16) & 1u);
  return (uint16_t)(u >> 16);
}

// JAX threefry2x32, key = (0, 42)
__device__ __forceinline__ void threefry(uint32_t x0, uint32_t x1,
                                         uint32_t& o0, uint32_t& o1) {
  const uint32_t ks0 = 0u;
  const uint32_t ks1 = 42u;
  const uint32_t ks2 = 0x1BD11BDAu ^ 42u;
  x0 += ks0; x1 += ks1;
#define TF_R(r) { x0 += x1; x1 = (x1 << r) | (x1 >> (32 - r)); x1 ^= x0; }
  TF_R(13) TF_R(15) TF_R(26) TF_R(6)
  x0 += ks1; x1 += ks2 + 1u;
  TF_R(17) TF_R(29) TF_R(16) TF_R(24)
  x0 += ks2; x1 += ks0 + 2u;
  TF_R(13) TF_R(15) TF_R(26) TF_R(6)
  x0 += ks0; x1 += ks1 + 3u;
  TF_R(17) TF_R(29) TF_R(16) TF_R(24)
  x0 += ks1; x1 += ks2 + 4u;
  TF_R(13) TF_R(15) TF_R(26) TF_R(6)
  x0 += ks2; x1 += ks0 + 5u;
#undef TF_R
  o0 = x0; o1 = x1;
}

// 2-bit modality index for output (b,e): argmax_f of (y0^y1)>>9,
// counts = (0, ((e<<12)+b)*4 + f)
__device__ __forceinline__ uint32_t pick_modality(uint32_t e, uint32_t b) {
  uint32_t base = ((e << 12) + b) << 2;
  uint32_t best = 0, bi = 0;
#pragma unroll
  for (uint32_t f = 0; f < 4; ++f) {
    uint32_t y0, y1;
    threefry(0u, base + f, y0, y1);
    uint32_t m = (y0 ^ y1) >> 9;
    if (f == 0) best = m;
    else if (m > best) { best = m; bi = f; }
  }
  return bi;
}

// x fp32 [B][K] -> bf16 [f][B][K]
__global__ __launch_bounds__(256) void convert_x(
    const float* __restrict__ x0, const float* __restrict__ x1,
    const float* __restrict__ x2, const float* __restrict__ x3,
    uint16_t* __restrict__ xb) {
  int f = blockIdx.z;
  const float* x = (f == 0) ? x0 : (f == 1) ? x1 : (f == 2) ? x2 : x3;
  size_t i = ((size_t)blockIdx.x * 256 + threadIdx.x) * 4;
  float4 v = *(const float4*)(x + i);
  union { uint16_t h[4]; uint64_t q; } p;
  p.h[0] = f2bf(v.x); p.h[1] = f2bf(v.y);
  p.h[2] = f2bf(v.z); p.h[3] = f2bf(v.w);
  *(uint64_t*)(xb + (size_t)f * B_DIM * K_DIM + i) = p.q;
}

// W fp32 [K][E] -> bf16 Wt [f][E][K]  (transpose via LDS tile)
__global__ __launch_bounds__(256) void convert_w(
    const float* __restrict__ W0, const float* __restrict__ W1,
    const float* __restrict__ W2, const float* __restrict__ W3,
    uint16_t* __restrict__ Wt) {
  __shared__ float tile[32][33];
  int f = blockIdx.z;
  const float* W = (f == 0) ? W0 : (f == 1) ? W1 : (f == 2) ? W2 : W3;
  int e0 = blockIdx.x * 32, k0 = blockIdx.y * 32;
  int tx = threadIdx.x, ty = threadIdx.y;
#pragma unroll
  for (int i = 0; i < 4; ++i)
    tile[ty + i * 8][tx] = W[(size_t)(k0 + ty + i * 8) * E_DIM + e0 + tx];
  __syncthreads();
  uint16_t* dst = Wt + (size_t)f * E_DIM * K_DIM;
#pragma unroll
  for (int i = 0; i < 4; ++i)
    dst[(size_t)(e0 + ty + i * 8) * K_DIM + k0 + tx] = f2bf(tile[tx][ty + i * 8]);
}

__device__ __forceinline__ void async16(const uint16_t* g, uint16_t* lds) {
  __builtin_amdgcn_global_load_lds(
      (const __attribute__((address_space(1))) void*)g,
      (__attribute__((address_space(3))) void*)lds, 16, 0, 0);
}

// One block: 128x128 output tile, loops f=0..3 (full K per f), selects
// per-element via in-block threefry, writes dense+coalesced once.
__global__ __launch_bounds__(256, 2) void gemm_fused(
    const uint16_t* __restrict__ Ab, const uint16_t* __restrict__ Bbt,
    const float* __restrict__ bias0, const float* __restrict__ bias1,
    const float* __restrict__ bias2, const float* __restrict__ bias3,
    float* __restrict__ out) {
  __shared__ uint16_t As[128 * 32];
  __shared__ uint16_t Bs[128 * 32];

  const int tid = threadIdx.x;
  const int w = tid >> 6;
  const int l = tid & 63;
  const int mBase = blockIdx.y * 128;
  const int nBase = blockIdx.x * 128;

  const int wm = (w >> 1) * 64, wn = (w & 1) * 64;
  const int ar = l >> 2, ac8 = l & 3;
  const int fr = l & 15, fq = l >> 4;

  // --- preload bias values bv[f][ni] (col = nBase+wn+ni*16+fr) ---
  float bv[4][4];
#pragma unroll
  for (int ni = 0; ni < 4; ++ni) {
    int col = nBase + wn + ni * 16 + fr;
    bv[0][ni] = bias0[col]; bv[1][ni] = bias1[col];
    bv[2][ni] = bias2[col]; bv[3][ni] = bias3[col];
  }

  // --- in-block idx: 64 outputs/lane, 2 bits each, packed per-ni ---
  uint32_t idxbits[4];
#pragma unroll
  for (int ni = 0; ni < 4; ++ni) {
    uint32_t e = nBase + wn + ni * 16 + fr;
    uint32_t word = 0;
#pragma unroll 1
    for (int mi = 0; mi < 4; ++mi) {
      uint32_t b0 = mBase + wm + mi * 16 + fq * 4;
#pragma unroll 1
      for (int r = 0; r < 4; ++r) {
        uint32_t bi = pick_modality(e, b0 + r);
        word |= bi << (2 * (mi * 4 + r));
      }
    }
    idxbits[ni] = word;
  }

  floatx4 res[4][4] = {};  // selected (+bias) results

#pragma unroll 1
  for (int f = 0; f < 4; ++f) {
    const uint16_t* A = Ab  + (size_t)f * B_DIM * K_DIM + (size_t)mBase * K_DIM;
    const uint16_t* B = Bbt + (size_t)f * E_DIM * K_DIM + (size_t)nBase * K_DIM;

    floatx4 acc[4][4] = {};
    for (int k0 = 0; k0 < K_DIM; k0 += 32) {
      #pragma unroll
      for (int t = 0; t < 2; ++t) {
        int c = w * 2 + t;
        async16(A + (size_t)(c * 16 + ar) * K_DIM + k0 + ac8 * 8, &As[c * 512]);
        async16(B + (size_t)(c * 16 + ar) * K_DIM + k0 + ac8 * 8, &Bs[c * 512]);
      }
      __syncthreads();

      short8 a[4], b[4];
      #pragma unroll
      for (int mi = 0; mi < 4; ++mi)
        a[mi] = *(const short8*)&As[(wm + mi * 16 + fr) * 32 + fq * 8];
      #pragma unroll
      for (int ni = 0; ni < 4; ++ni)
        b[ni] = *(const short8*)&Bs[(wn + ni * 16 + fr) * 32 + fq * 8];
      #pragma unroll
      for (int mi = 0; mi < 4; ++mi)
        #pragma unroll
        for (int ni = 0; ni < 4; ++ni)
          acc[mi][ni] = __builtin_amdgcn_mfma_f32_16x16x32_bf16(
              a[mi], b[ni], acc[mi][ni], 0, 0, 0);
      __syncthreads();
    }

    // merge: keep acc+bias where idx == f
    #pragma unroll
    for (int ni = 0; ni < 4; ++ni) {
      float bvf = bv[f][ni];
      uint32_t word = idxbits[ni];
      #pragma unroll
      for (int mi = 0; mi < 4; ++mi)
        #pragma unroll
        for (int r = 0; r < 4; ++r) {
          uint32_t sel = (word >> (2 * (mi * 4 + r))) & 3u;
          if (sel == (uint32_t)f) res[mi][ni][r] = acc[mi][ni][r] + bvf;
        }
    }
  }

  // dense coalesced store with relu. C/D: col=lane&15, row=(lane>>4)*4+reg
#pragma unroll
  for (int ni = 0; ni < 4; ++ni) {
    int col = nBase + wn + ni * 16 + fr;
#pragma unroll
    for (int mi = 0; mi < 4; ++mi) {
      int row0 = mBase + wm + mi * 16 + fq * 4;
#pragma unroll
      for (int r = 0; r < 4; ++r) {
        float o = res[mi][ni][r];
        out[(size_t)(row0 + r) * E_DIM + col] = o > 0.f ? o : 0.f;
      }
    }
  }
}

extern "C" void kernel_launch(void* const* d_in, const int* in_sizes, int n_in,
                              void* d_out, int out_size, void* d_ws, size_t ws_size,
                              hipStream_t stream) {
  const float* x[4]; const float* W[4]; const float* bs[4];
  for (int f = 0; f < 4; ++f) {
    x[f]  = (const float*)d_in[3 * f + 0];
    W[f]  = (const float*)d_in[3 * f + 1];
    bs[f] = (const float*)d_in[3 * f + 2];
  }
  char* ws = (char*)d_ws;
  uint16_t* xb = (uint16_t*)ws;                               // 32 MB
  uint16_t* Wt = (uint16_t*)(ws + (size_t)32 * 1024 * 1024);  // 16 MB
  float* out = (float*)d_out;

  convert_x<<<dim3(4096, 1, 4), dim3(256), 0, stream>>>(x[0], x[1], x[2], x[3], xb);
  convert_w<<<dim3(64, 32, 4), dim3(32, 8), 0, stream>>>(W[0], W[1], W[2], W[3], Wt);
  gemm_fused<<<dim3(E_DIM / 128, B_DIM / 128), dim3(256), 0, stream>>>(
      xb, Wt, bs[0], bs[1], bs[2], bs[3], out);
}

// Round 6
// 309.226 us; speedup vs baseline: 1.0704x; 1.0116x over previous
//
#include <hip/hip_runtime.h>
#include <stdint.h>

// ---------------------------------------------------------------------------
// EmbraceNet fused: out[b,e] = relu(x_f @ W_f + b_f)[b,e],  f = idx[b,e]
// idx = categorical(key=42, uniform): partitionable threefry, bits = y0^y1
// of threefry2x32((0,42), (0, (e*4096+b)*4+f)); argmax over bits>>9 with
// strict > (first-index tie-break) — exact (verified PASS R4/R5).
//
// R6: threefry back in a standalone full-occupancy kernel (R5 showed in-block
// threefry at 2 waves/SIMD is latency-bound: VALUBusy 80us vs 35us floor),
// but packed to 2 bits/output (idx2[e][b/16] dwords, 2MB) so the GEMM
// epilogue reads 16 L2-hot dwords/lane instead of recomputing. GEMM keeps
// R5's f-inside-block dense single write (WRITE_SIZE 150->44MB win).
// ---------------------------------------------------------------------------

typedef short short8 __attribute__((ext_vector_type(8)));
typedef float floatx4 __attribute__((ext_vector_type(4)));

#define B_DIM 4096
#define K_DIM 1024
#define E_DIM 2048

__device__ __forceinline__ uint16_t f2bf(float x) {
  uint32_t u = __float_as_uint(x);
  u += 0x7FFFu + ((u >> 16) & 1u);
  return (uint16_t)(u >> 16);
}

// JAX threefry2x32, key = (0, 42)
__device__ __forceinline__ void threefry(uint32_t x0, uint32_t x1,
                                         uint32_t& o0, uint32_t& o1) {
  const uint32_t ks0 = 0u;
  const uint32_t ks1 = 42u;
  const uint32_t ks2 = 0x1BD11BDAu ^ 42u;
  x0 += ks0; x1 += ks1;
#define TF_R(r) { x0 += x1; x1 = (x1 << r) | (x1 >> (32 - r)); x1 ^= x0; }
  TF_R(13) TF_R(15) TF_R(26) TF_R(6)
  x0 += ks1; x1 += ks2 + 1u;
  TF_R(17) TF_R(29) TF_R(16) TF_R(24)
  x0 += ks2; x1 += ks0 + 2u;
  TF_R(13) TF_R(15) TF_R(26) TF_R(6)
  x0 += ks0; x1 += ks1 + 3u;
  TF_R(17) TF_R(29) TF_R(16) TF_R(24)
  x0 += ks1; x1 += ks2 + 4u;
  TF_R(13) TF_R(15) TF_R(26) TF_R(6)
  x0 += ks2; x1 += ks0 + 5u;
#undef TF_R
  o0 = x0; o1 = x1;
}

// idx2[tid], tid = e*256 + b_hi: 2-bit sel for b = b_hi*16+j at bits 2j.
// Flat gumbel i = (e*4096 + b)*4 + f = tid*64 + j*4 + f.
__global__ __launch_bounds__(256) void idx_kernel(uint32_t* __restrict__ idx2) {
  uint32_t tid = blockIdx.x * 256u + threadIdx.x;  // 0 .. 2^19-1
  uint32_t base = tid << 6;
  uint32_t word = 0;
#pragma unroll 2
  for (int j = 0; j < 16; ++j) {
    uint32_t c = base + 4u * j;
    uint32_t best = 0, bi = 0;
#pragma unroll
    for (uint32_t f = 0; f < 4; ++f) {  // 4 independent chains -> ILP
      uint32_t y0, y1;
      threefry(0u, c + f, y0, y1);
      uint32_t m = (y0 ^ y1) >> 9;
      if (f == 0) best = m;
      else if (m > best) { best = m; bi = f; }
    }
    word |= bi << (2 * j);
  }
  idx2[tid] = word;
}

// x fp32 [B][K] -> bf16 [f][B][K]
__global__ __launch_bounds__(256) void convert_x(
    const float* __restrict__ x0, const float* __restrict__ x1,
    const float* __restrict__ x2, const float* __restrict__ x3,
    uint16_t* __restrict__ xb) {
  int f = blockIdx.z;
  const float* x = (f == 0) ? x0 : (f == 1) ? x1 : (f == 2) ? x2 : x3;
  size_t i = ((size_t)blockIdx.x * 256 + threadIdx.x) * 4;
  float4 v = *(const float4*)(x + i);
  union { uint16_t h[4]; uint64_t q; } p;
  p.h[0] = f2bf(v.x); p.h[1] = f2bf(v.y);
  p.h[2] = f2bf(v.z); p.h[3] = f2bf(v.w);
  *(uint64_t*)(xb + (size_t)f * B_DIM * K_DIM + i) = p.q;
}

// W fp32 [K][E] -> bf16 Wt [f][E][K]  (transpose via LDS tile)
__global__ __launch_bounds__(256) void convert_w(
    const float* __restrict__ W0, const float* __restrict__ W1,
    const float* __restrict__ W2, const float* __restrict__ W3,
    uint16_t* __restrict__ Wt) {
  __shared__ float tile[32][33];
  int f = blockIdx.z;
  const float* W = (f == 0) ? W0 : (f == 1) ? W1 : (f == 2) ? W2 : W3;
  int e0 = blockIdx.x * 32, k0 = blockIdx.y * 32;
  int tx = threadIdx.x, ty = threadIdx.y;
#pragma unroll
  for (int i = 0; i < 4; ++i)
    tile[ty + i * 8][tx] = W[(size_t)(k0 + ty + i * 8) * E_DIM + e0 + tx];
  __syncthreads();
  uint16_t* dst = Wt + (size_t)f * E_DIM * K_DIM;
#pragma unroll
  for (int i = 0; i < 4; ++i)
    dst[(size_t)(e0 + ty + i * 8) * K_DIM + k0 + tx] = f2bf(tile[tx][ty + i * 8]);
}

__device__ __forceinline__ void async16(const uint16_t* g, uint16_t* lds) {
  __builtin_amdgcn_global_load_lds(
      (const __attribute__((address_space(1))) void*)g,
      (__attribute__((address_space(3))) void*)lds, 16, 0, 0);
}

// One block: 128x128 output tile, f-loop inside (full K per f), select via
// packed idx2 words, dense coalesced single write.
__global__ __launch_bounds__(256, 2) void gemm_fused(
    const uint16_t* __restrict__ Ab, const uint16_t* __restrict__ Bbt,
    const uint32_t* __restrict__ idx2,
    const float* __restrict__ bias0, const float* __restrict__ bias1,
    const float* __restrict__ bias2, const float* __restrict__ bias3,
    float* __restrict__ out) {
  __shared__ uint16_t As[128 * 32];
  __shared__ uint16_t Bs[128 * 32];

  const int tid = threadIdx.x;
  const int w = tid >> 6;
  const int l = tid & 63;
  const int mBase = blockIdx.y * 128;
  const int nBase = blockIdx.x * 128;

  const int wm = (w >> 1) * 64, wn = (w & 1) * 64;
  const int ar = l >> 2, ac8 = l & 3;
  const int fr = l & 15, fq = l >> 4;

  // idx words: iw[ni][mi] covers col = nBase+wn+ni*16+fr, rows b_hi0+mi.
  const int b_hi0 = (mBase + wm) >> 4;
  uint32_t iw[4][4];
#pragma unroll
  for (int ni = 0; ni < 4; ++ni) {
    int col = nBase + wn + ni * 16 + fr;
#pragma unroll
    for (int mi = 0; mi < 4; ++mi)
      iw[ni][mi] = idx2[(size_t)col * (B_DIM / 16) + b_hi0 + mi];
  }

  floatx4 res[4][4] = {};  // selected relu(acc+bias) results

#pragma unroll 1
  for (int f = 0; f < 4; ++f) {
    const uint16_t* A = Ab  + (size_t)f * B_DIM * K_DIM + (size_t)mBase * K_DIM;
    const uint16_t* B = Bbt + (size_t)f * E_DIM * K_DIM + (size_t)nBase * K_DIM;

    floatx4 acc[4][4] = {};
    for (int k0 = 0; k0 < K_DIM; k0 += 32) {
      #pragma unroll
      for (int t = 0; t < 2; ++t) {
        int c = w * 2 + t;
        async16(A + (size_t)(c * 16 + ar) * K_DIM + k0 + ac8 * 8, &As[c * 512]);
        async16(B + (size_t)(c * 16 + ar) * K_DIM + k0 + ac8 * 8, &Bs[c * 512]);
      }
      __syncthreads();

      short8 a[4], b[4];
      #pragma unroll
      for (int mi = 0; mi < 4; ++mi)
        a[mi] = *(const short8*)&As[(wm + mi * 16 + fr) * 32 + fq * 8];
      #pragma unroll
      for (int ni = 0; ni < 4; ++ni)
        b[ni] = *(const short8*)&Bs[(wn + ni * 16 + fr) * 32 + fq * 8];
      #pragma unroll
      for (int mi = 0; mi < 4; ++mi)
        #pragma unroll
        for (int ni = 0; ni < 4; ++ni)
          acc[mi][ni] = __builtin_amdgcn_mfma_f32_16x16x32_bf16(
              a[mi], b[ni], acc[mi][ni], 0, 0, 0);
      __syncthreads();
    }

    // merge: keep acc+bias where idx == f  (bias loaded per f: L2-hot)
    const float* bias = (f == 0) ? bias0 : (f == 1) ? bias1
                      : (f == 2) ? bias2 : bias3;
    #pragma unroll
    for (int ni = 0; ni < 4; ++ni) {
      float bvf = bias[nBase + wn + ni * 16 + fr];
      #pragma unroll
      for (int mi = 0; mi < 4; ++mi) {
        uint32_t wd = iw[ni][mi];
        #pragma unroll
        for (int r = 0; r < 4; ++r) {
          uint32_t sel = (wd >> (2 * (fq * 4 + r))) & 3u;
          if (sel == (uint32_t)f) res[mi][ni][r] = acc[mi][ni][r] + bvf;
        }
      }
    }
  }

  // dense coalesced store with relu. C/D: col=lane&15, row=(lane>>4)*4+reg
#pragma unroll
  for (int ni = 0; ni < 4; ++ni) {
    int col = nBase + wn + ni * 16 + fr;
#pragma unroll
    for (int mi = 0; mi < 4; ++mi) {
      int row0 = mBase + wm + mi * 16 + fq * 4;
#pragma unroll
      for (int r = 0; r < 4; ++r) {
        float o = res[mi][ni][r];
        __builtin_nontemporal_store(o > 0.f ? o : 0.f,
                                    &out[(size_t)(row0 + r) * E_DIM + col]);
      }
    }
  }
}

extern "C" void kernel_launch(void* const* d_in, const int* in_sizes, int n_in,
                              void* d_out, int out_size, void* d_ws, size_t ws_size,
                              hipStream_t stream) {
  const float* x[4]; const float* W[4]; const float* bs[4];
  for (int f = 0; f < 4; ++f) {
    x[f]  = (const float*)d_in[3 * f + 0];
    W[f]  = (const float*)d_in[3 * f + 1];
    bs[f] = (const float*)d_in[3 * f + 2];
  }
  char* ws = (char*)d_ws;
  uint16_t* xb  = (uint16_t*)ws;                               // 32 MB
  uint16_t* Wt  = (uint16_t*)(ws + (size_t)32 * 1024 * 1024);  // 16 MB
  uint32_t* idx2 = (uint32_t*)(ws + (size_t)48 * 1024 * 1024); //  2 MB
  float* out = (float*)d_out;

  idx_kernel<<<dim3(2048), dim3(256), 0, stream>>>(idx2);
  convert_x<<<dim3(4096, 1, 4), dim3(256), 0, stream>>>(x[0], x[1], x[2], x[3], xb);
  convert_w<<<dim3(64, 32, 4), dim3(32, 8), 0, stream>>>(W[0], W[1], W[2], W[3], Wt);
  gemm_fused<<<dim3(E_DIM / 128, B_DIM / 128), dim3(256), 0, stream>>>(
      xb, Wt, idx2, bs[0], bs[1], bs[2], bs[3], out);
}

// Round 7
// 306.156 us; speedup vs baseline: 1.0811x; 1.0100x over previous
//
#include <hip/hip_runtime.h>
#include <stdint.h>

// ---------------------------------------------------------------------------
// EmbraceNet fused: out[b,e] = relu(x_f @ W_f + b_f)[b,e],  f = idx[b,e]
// idx = categorical(key=42): partitionable threefry, bits = y0^y1 of
// threefry2x32((0,42), (0, (e*4096+b)*4+f)); argmax over bits>>9, strict >
// (first-index tie-break) — exact. PASS since R4 (absmax 0.031).
//
// R7: gemm rebuilt for TLP: 512-thread blocks (8 waves, 2x4), 4 waves/SIMD
// (R6 ran at 2), double-buffered LDS, ONE barrier per k-iter with next-tile
// global_load_lds issued before compute so the barrier's vmcnt(0) drain
// lands after a compute phase. idx unroll x4; converts merged to 1 dispatch.
// ---------------------------------------------------------------------------

typedef short short8 __attribute__((ext_vector_type(8)));
typedef float floatx4 __attribute__((ext_vector_type(4)));

#define B_DIM 4096
#define K_DIM 1024
#define E_DIM 2048

__device__ __forceinline__ uint16_t f2bf(float x) {
  uint32_t u = __float_as_uint(x);
  u += 0x7FFFu + ((u >> 16) & 1u);
  return (uint16_t)(u >> 16);
}

// JAX threefry2x32, key = (0, 42)
__device__ __forceinline__ void threefry(uint32_t x0, uint32_t x1,
                                         uint32_t& o0, uint32_t& o1) {
  const uint32_t ks0 = 0u;
  const uint32_t ks1 = 42u;
  const uint32_t ks2 = 0x1BD11BDAu ^ 42u;
  x0 += ks0; x1 += ks1;
#define TF_R(r) { x0 += x1; x1 = (x1 << r) | (x1 >> (32 - r)); x1 ^= x0; }
  TF_R(13) TF_R(15) TF_R(26) TF_R(6)
  x0 += ks1; x1 += ks2 + 1u;
  TF_R(17) TF_R(29) TF_R(16) TF_R(24)
  x0 += ks2; x1 += ks0 + 2u;
  TF_R(13) TF_R(15) TF_R(26) TF_R(6)
  x0 += ks0; x1 += ks1 + 3u;
  TF_R(17) TF_R(29) TF_R(16) TF_R(24)
  x0 += ks1; x1 += ks2 + 4u;
  TF_R(13) TF_R(15) TF_R(26) TF_R(6)
  x0 += ks2; x1 += ks0 + 5u;
#undef TF_R
  o0 = x0; o1 = x1;
}

// idx2[tid], tid = e*256 + b_hi: 2-bit sel for b = b_hi*16+j at bits 2j.
__global__ __launch_bounds__(256) void idx_kernel(uint32_t* __restrict__ idx2) {
  uint32_t tid = blockIdx.x * 256u + threadIdx.x;  // 0 .. 2^19-1
  uint32_t base = tid << 6;
  uint32_t word = 0;
#pragma unroll 4
  for (int j = 0; j < 16; ++j) {
    uint32_t c = base + 4u * j;
    uint32_t best = 0, bi = 0;
#pragma unroll
    for (uint32_t f = 0; f < 4; ++f) {
      uint32_t y0, y1;
      threefry(0u, c + f, y0, y1);
      uint32_t m = (y0 ^ y1) >> 9;
      if (f == 0) best = m;
      else if (m > best) { best = m; bi = f; }
    }
    word |= bi << (2 * j);
  }
  idx2[tid] = word;
}

// One dispatch: z<4 -> x plane z (fp32[B][K] -> bf16 [f][B][K]);
//               z>=4 -> W plane z-4 (fp32[K][E] -> bf16 Wt [f][E][K], transpose)
__global__ __launch_bounds__(256) void convert_all(
    const float* __restrict__ x0, const float* __restrict__ x1,
    const float* __restrict__ x2, const float* __restrict__ x3,
    const float* __restrict__ W0, const float* __restrict__ W1,
    const float* __restrict__ W2, const float* __restrict__ W3,
    uint16_t* __restrict__ xb, uint16_t* __restrict__ Wt) {
  int z = blockIdx.z;
  if (z < 4) {
    const float* x = (z == 0) ? x0 : (z == 1) ? x1 : (z == 2) ? x2 : x3;
    size_t i = ((size_t)blockIdx.x * 256 + threadIdx.x) * 4;
    float4 v = *(const float4*)(x + i);
    union { uint16_t h[4]; uint64_t q; } p;
    p.h[0] = f2bf(v.x); p.h[1] = f2bf(v.y);
    p.h[2] = f2bf(v.z); p.h[3] = f2bf(v.w);
    *(uint64_t*)(xb + (size_t)z * B_DIM * K_DIM + i) = p.q;
  } else {
    if (blockIdx.x >= 2048) return;
    int f = z - 4;
    const float* W = (f == 0) ? W0 : (f == 1) ? W1 : (f == 2) ? W2 : W3;
    __shared__ float tile[32][33];
    int e0 = (blockIdx.x & 63) * 32, k0 = (blockIdx.x >> 6) * 32;
    int tx = threadIdx.x & 31, ty = threadIdx.x >> 5;
#pragma unroll
    for (int i = 0; i < 4; ++i)
      tile[ty + i * 8][tx] = W[(size_t)(k0 + ty + i * 8) * E_DIM + e0 + tx];
    __syncthreads();
    // writeout: 8B per thread, coalesced. t -> (e_local = t>>3, k chunk = t&7)
    int t = threadIdx.x;
    int el = t >> 3, kc = (t & 7) * 4;
    union { uint16_t h[4]; uint64_t q; } p;
#pragma unroll
    for (int i = 0; i < 4; ++i) p.h[i] = f2bf(tile[kc + i][el]);
    uint16_t* dst = Wt + (size_t)f * E_DIM * K_DIM;
    *(uint64_t*)(dst + (size_t)(e0 + el) * K_DIM + k0 + kc) = p.q;
  }
}

__device__ __forceinline__ void async16(const uint16_t* g, uint16_t* lds) {
  __builtin_amdgcn_global_load_lds(
      (const __attribute__((address_space(1))) void*)g,
      (__attribute__((address_space(3))) void*)lds, 16, 0, 0);
}

// 512 threads (8 waves, 2x4; wave-tile 64x32), 128x128 tile, f-loop inside,
// double-buffered LDS, one barrier per k-iter.
__global__ __launch_bounds__(512, 4) void gemm_fused(
    const uint16_t* __restrict__ Ab, const uint16_t* __restrict__ Bbt,
    const uint32_t* __restrict__ idx2,
    const float* __restrict__ bias0, const float* __restrict__ bias1,
    const float* __restrict__ bias2, const float* __restrict__ bias3,
    float* __restrict__ out) {
  __shared__ uint16_t As[2][128 * 32];
  __shared__ uint16_t Bs[2][128 * 32];

  const int tid = threadIdx.x;
  const int w = tid >> 6;        // 0..7
  const int l = tid & 63;
  const int mBase = blockIdx.y * 128;
  const int nBase = blockIdx.x * 128;

  const int wm = (w >> 2) * 64;  // 0 or 64
  const int wn = (w & 3) * 32;   // 0,32,64,96
  const int sr = l >> 2, sc8 = l & 3;  // staging: row-in-16, 8-col chunk
  const int fr = l & 15, fq = l >> 4;

  // idx words: iw[ni][mi], ni over 2 col groups, mi over 4 row groups of 16
  const int b_hi0 = (mBase + wm) >> 4;
  uint32_t iw[2][4];
#pragma unroll
  for (int ni = 0; ni < 2; ++ni) {
    int col = nBase + wn + ni * 16 + fr;
#pragma unroll
    for (int mi = 0; mi < 4; ++mi)
      iw[ni][mi] = idx2[(size_t)col * (B_DIM / 16) + b_hi0 + mi];
  }

  floatx4 res[4][2] = {};

#pragma unroll 1
  for (int f = 0; f < 4; ++f) {
    const uint16_t* A = Ab  + (size_t)f * B_DIM * K_DIM + (size_t)mBase * K_DIM;
    const uint16_t* B = Bbt + (size_t)f * E_DIM * K_DIM + (size_t)nBase * K_DIM;
    // wave w stages rows [16w..16w+16) of both tiles: one async16 each.
    const uint16_t* Aw = A + (size_t)(16 * w + sr) * K_DIM + sc8 * 8;
    const uint16_t* Bw = B + (size_t)(16 * w + sr) * K_DIM + sc8 * 8;

    floatx4 acc[4][2] = {};

    async16(Aw, &As[0][w * 512]);
    async16(Bw, &Bs[0][w * 512]);
    __syncthreads();  // buf0 ready

    int buf = 0;
#pragma unroll 1
    for (int kt = 0; kt < 32; ++kt) {
      int k0 = kt * 32;
      if (kt + 1 < 32) {  // issue next tile before computing current
        async16(Aw + k0 + 32, &As[buf ^ 1][w * 512]);
        async16(Bw + k0 + 32, &Bs[buf ^ 1][w * 512]);
      }
      short8 a[4], b[2];
      #pragma unroll
      for (int mi = 0; mi < 4; ++mi)
        a[mi] = *(const short8*)&As[buf][(wm + mi * 16 + fr) * 32 + fq * 8];
      #pragma unroll
      for (int ni = 0; ni < 2; ++ni)
        b[ni] = *(const short8*)&Bs[buf][(wn + ni * 16 + fr) * 32 + fq * 8];
      #pragma unroll
      for (int mi = 0; mi < 4; ++mi)
        #pragma unroll
        for (int ni = 0; ni < 2; ++ni)
          acc[mi][ni] = __builtin_amdgcn_mfma_f32_16x16x32_bf16(
              a[mi], b[ni], acc[mi][ni], 0, 0, 0);
      __syncthreads();  // drains next-tile loads (after compute) + read-done
      buf ^= 1;
    }

    const float* bias = (f == 0) ? bias0 : (f == 1) ? bias1
                      : (f == 2) ? bias2 : bias3;
    #pragma unroll
    for (int ni = 0; ni < 2; ++ni) {
      float bvf = bias[nBase + wn + ni * 16 + fr];
      #pragma unroll
      for (int mi = 0; mi < 4; ++mi) {
        uint32_t wd = iw[ni][mi];
        #pragma unroll
        for (int r = 0; r < 4; ++r) {
          uint32_t sel = (wd >> (2 * (fq * 4 + r))) & 3u;
          if (sel == (uint32_t)f) res[mi][ni][r] = acc[mi][ni][r] + bvf;
        }
      }
    }
  }

  // dense coalesced store with relu. C/D: col=lane&15, row=(lane>>4)*4+reg
#pragma unroll
  for (int ni = 0; ni < 2; ++ni) {
    int col = nBase + wn + ni * 16 + fr;
#pragma unroll
    for (int mi = 0; mi < 4; ++mi) {
      int row0 = mBase + wm + mi * 16 + fq * 4;
#pragma unroll
      for (int r = 0; r < 4; ++r) {
        float o = res[mi][ni][r];
        __builtin_nontemporal_store(o > 0.f ? o : 0.f,
                                    &out[(size_t)(row0 + r) * E_DIM + col]);
      }
    }
  }
}

extern "C" void kernel_launch(void* const* d_in, const int* in_sizes, int n_in,
                              void* d_out, int out_size, void* d_ws, size_t ws_size,
                              hipStream_t stream) {
  const float* x[4]; const float* W[4]; const float* bs[4];
  for (int f = 0; f < 4; ++f) {
    x[f]  = (const float*)d_in[3 * f + 0];
    W[f]  = (const float*)d_in[3 * f + 1];
    bs[f] = (const float*)d_in[3 * f + 2];
  }
  char* ws = (char*)d_ws;
  uint16_t* xb  = (uint16_t*)ws;                               // 32 MB
  uint16_t* Wt  = (uint16_t*)(ws + (size_t)32 * 1024 * 1024);  // 16 MB
  uint32_t* idx2 = (uint32_t*)(ws + (size_t)48 * 1024 * 1024); //  2 MB
  float* out = (float*)d_out;

  idx_kernel<<<dim3(2048), dim3(256), 0, stream>>>(idx2);
  convert_all<<<dim3(4096, 1, 8), dim3(256), 0, stream>>>(
      x[0], x[1], x[2], x[3], W[0], W[1], W[2], W[3], xb, Wt);
  gemm_fused<<<dim3(E_DIM / 128, B_DIM / 128), dim3(512), 0, stream>>>(
      xb, Wt, idx2, bs[0], bs[1], bs[2], bs[3], out);
}

// Round 8
// 303.193 us; speedup vs baseline: 1.0917x; 1.0098x over previous
//
#include <hip/hip_runtime.h>
#include <stdint.h>

// ---------------------------------------------------------------------------
// EmbraceNet fused: out[b,e] = relu(x_f @ W_f + b_f)[b,e],  f = idx[b,e]
// idx = categorical(key=42): partitionable threefry, bits = y0^y1 of
// threefry2x32((0,42), (0, (e*4096+b)*4+f)); argmax over bits>>9, strict >.
// PASS since R4 (absmax 0.031).
//
// R8: (1) idx + x/W converts merged into ONE dispatch, block types
// interleaved 1:8:4 (period 13) so VALU-bound idx co-schedules with
// HBM-bound converts (m114 overlap). (2) GEMM LDS XOR-swizzle: staging lane
// loads global chunk (l&3)^((l>>3)&3), reads use fq^((fr>>1)&3) — breaks the
// row-stride bank aliasing behind 12.6M SQ_LDS_BANK_CONFLICT cycles.
// ---------------------------------------------------------------------------

typedef short short8 __attribute__((ext_vector_type(8)));
typedef float floatx4 __attribute__((ext_vector_type(4)));

#define B_DIM 4096
#define K_DIM 1024
#define E_DIM 2048

__device__ __forceinline__ uint16_t f2bf(float x) {
  uint32_t u = __float_as_uint(x);
  u += 0x7FFFu + ((u >> 16) & 1u);
  return (uint16_t)(u >> 16);
}

// JAX threefry2x32, key = (0, 42)
__device__ __forceinline__ void threefry(uint32_t x0, uint32_t x1,
                                         uint32_t& o0, uint32_t& o1) {
  const uint32_t ks0 = 0u;
  const uint32_t ks1 = 42u;
  const uint32_t ks2 = 0x1BD11BDAu ^ 42u;
  x0 += ks0; x1 += ks1;
#define TF_R(r) { x0 += x1; x1 = (x1 << r) | (x1 >> (32 - r)); x1 ^= x0; }
  TF_R(13) TF_R(15) TF_R(26) TF_R(6)
  x0 += ks1; x1 += ks2 + 1u;
  TF_R(17) TF_R(29) TF_R(16) TF_R(24)
  x0 += ks2; x1 += ks0 + 2u;
  TF_R(13) TF_R(15) TF_R(26) TF_R(6)
  x0 += ks0; x1 += ks1 + 3u;
  TF_R(17) TF_R(29) TF_R(16) TF_R(24)
  x0 += ks1; x1 += ks2 + 4u;
  TF_R(13) TF_R(15) TF_R(26) TF_R(6)
  x0 += ks2; x1 += ks0 + 5u;
#undef TF_R
  o0 = x0; o1 = x1;
}

// One dispatch, 26624 blocks, period-13 type pattern:
//   slot 0      -> idx     (2048 chunks)
//   slots 1..8  -> x conv  (16384 blocks: 4 planes x 4096)
//   slots 9..12 -> W conv  (8192 blocks: 4 planes x 2048)
__global__ __launch_bounds__(256) void prep_kernel(
    const float* __restrict__ x0, const float* __restrict__ x1,
    const float* __restrict__ x2, const float* __restrict__ x3,
    const float* __restrict__ W0, const float* __restrict__ W1,
    const float* __restrict__ W2, const float* __restrict__ W3,
    uint16_t* __restrict__ xb, uint16_t* __restrict__ Wt,
    uint32_t* __restrict__ idx2) {
  __shared__ float tile[32][33];
  const uint32_t g = blockIdx.x;
  const uint32_t chunk = g / 13u, slot = g % 13u;
  const int t = threadIdx.x;

  if (slot == 0) {
    // idx2[tid], tid = e*256 + b_hi: 2-bit sel for b = b_hi*16+j at bits 2j
    uint32_t tid = chunk * 256u + t;
    uint32_t base = tid << 6;
    uint32_t word = 0;
#pragma unroll 4
    for (int j = 0; j < 16; ++j) {
      uint32_t c = base + 4u * j;
      uint32_t best = 0, bi = 0;
#pragma unroll
      for (uint32_t f = 0; f < 4; ++f) {
        uint32_t y0, y1;
        threefry(0u, c + f, y0, y1);
        uint32_t m = (y0 ^ y1) >> 9;
        if (f == 0) best = m;
        else if (m > best) { best = m; bi = f; }
      }
      word |= bi << (2 * j);
    }
    idx2[tid] = word;
  } else if (slot <= 8) {
    uint32_t xi = chunk * 8u + (slot - 1);        // 0..16383
    int f = xi >> 12;
    const float* x = (f == 0) ? x0 : (f == 1) ? x1 : (f == 2) ? x2 : x3;
    size_t i = ((size_t)(xi & 4095) * 256 + t) * 4;
    float4 v = *(const float4*)(x + i);
    union { uint16_t h[4]; uint64_t q; } p;
    p.h[0] = f2bf(v.x); p.h[1] = f2bf(v.y);
    p.h[2] = f2bf(v.z); p.h[3] = f2bf(v.w);
    *(uint64_t*)(xb + (size_t)f * B_DIM * K_DIM + i) = p.q;
  } else {
    uint32_t wi = chunk * 4u + (slot - 9);        // 0..8191
    int f = wi >> 11;
    uint32_t ip = wi & 2047;
    const float* W = (f == 0) ? W0 : (f == 1) ? W1 : (f == 2) ? W2 : W3;
    int e0 = (ip & 63) * 32, k0 = (ip >> 6) * 32;
    int tx = t & 31, ty = t >> 5;
#pragma unroll
    for (int i = 0; i < 4; ++i)
      tile[ty + i * 8][tx] = W[(size_t)(k0 + ty + i * 8) * E_DIM + e0 + tx];
    __syncthreads();
    int el = t >> 3, kc = (t & 7) * 4;
    union { uint16_t h[4]; uint64_t q; } p;
#pragma unroll
    for (int i = 0; i < 4; ++i) p.h[i] = f2bf(tile[kc + i][el]);
    uint16_t* dst = Wt + (size_t)f * E_DIM * K_DIM;
    *(uint64_t*)(dst + (size_t)(e0 + el) * K_DIM + k0 + kc) = p.q;
  }
}

__device__ __forceinline__ void async16(const uint16_t* g, uint16_t* lds) {
  __builtin_amdgcn_global_load_lds(
      (const __attribute__((address_space(1))) void*)g,
      (__attribute__((address_space(3))) void*)lds, 16, 0, 0);
}

// 512 threads (8 waves, 2x4; wave-tile 64x32), 128x128 tile, f-loop inside,
// double-buffered LDS, one barrier per k-iter, XOR-swizzled LDS layout.
__global__ __launch_bounds__(512, 4) void gemm_fused(
    const uint16_t* __restrict__ Ab, const uint16_t* __restrict__ Bbt,
    const uint32_t* __restrict__ idx2,
    const float* __restrict__ bias0, const float* __restrict__ bias1,
    const float* __restrict__ bias2, const float* __restrict__ bias3,
    float* __restrict__ out) {
  __shared__ uint16_t As[2][128 * 32];
  __shared__ uint16_t Bs[2][128 * 32];

  const int tid = threadIdx.x;
  const int w = tid >> 6;        // 0..7
  const int l = tid & 63;
  const int mBase = blockIdx.y * 128;
  const int nBase = blockIdx.x * 128;

  const int wm = (w >> 2) * 64;  // 0 or 64
  const int wn = (w & 3) * 32;   // 0,32,64,96
  // staging with XOR swizzle: lane l -> row sr, global chunk sc8
  const int sr = l >> 2;
  const int sc8 = (l & 3) ^ ((l >> 3) & 3);
  const int fr = l & 15, fq = l >> 4;
  const int fqs = (fq ^ ((fr >> 1) & 3)) * 8;  // swizzled read chunk offset

  const int b_hi0 = (mBase + wm) >> 4;
  uint32_t iw[2][4];
#pragma unroll
  for (int ni = 0; ni < 2; ++ni) {
    int col = nBase + wn + ni * 16 + fr;
#pragma unroll
    for (int mi = 0; mi < 4; ++mi)
      iw[ni][mi] = idx2[(size_t)col * (B_DIM / 16) + b_hi0 + mi];
  }

  floatx4 res[4][2] = {};

#pragma unroll 1
  for (int f = 0; f < 4; ++f) {
    const uint16_t* A = Ab  + (size_t)f * B_DIM * K_DIM + (size_t)mBase * K_DIM;
    const uint16_t* B = Bbt + (size_t)f * E_DIM * K_DIM + (size_t)nBase * K_DIM;
    const uint16_t* Aw = A + (size_t)(16 * w + sr) * K_DIM + sc8 * 8;
    const uint16_t* Bw = B + (size_t)(16 * w + sr) * K_DIM + sc8 * 8;

    floatx4 acc[4][2] = {};

    async16(Aw, &As[0][w * 512]);
    async16(Bw, &Bs[0][w * 512]);
    __syncthreads();

    int buf = 0;
#pragma unroll 1
    for (int kt = 0; kt < 32; ++kt) {
      int k0 = kt * 32;
      if (kt + 1 < 32) {
        async16(Aw + k0 + 32, &As[buf ^ 1][w * 512]);
        async16(Bw + k0 + 32, &Bs[buf ^ 1][w * 512]);
      }
      short8 a[4], b[2];
      #pragma unroll
      for (int mi = 0; mi < 4; ++mi)
        a[mi] = *(const short8*)&As[buf][(wm + mi * 16 + fr) * 32 + fqs];
      #pragma unroll
      for (int ni = 0; ni < 2; ++ni)
        b[ni] = *(const short8*)&Bs[buf][(wn + ni * 16 + fr) * 32 + fqs];
      #pragma unroll
      for (int mi = 0; mi < 4; ++mi)
        #pragma unroll
        for (int ni = 0; ni < 2; ++ni)
          acc[mi][ni] = __builtin_amdgcn_mfma_f32_16x16x32_bf16(
              a[mi], b[ni], acc[mi][ni], 0, 0, 0);
      __syncthreads();
      buf ^= 1;
    }

    const float* bias = (f == 0) ? bias0 : (f == 1) ? bias1
                      : (f == 2) ? bias2 : bias3;
    #pragma unroll
    for (int ni = 0; ni < 2; ++ni) {
      float bvf = bias[nBase + wn + ni * 16 + fr];
      #pragma unroll
      for (int mi = 0; mi < 4; ++mi) {
        uint32_t wd = iw[ni][mi];
        #pragma unroll
        for (int r = 0; r < 4; ++r) {
          uint32_t sel = (wd >> (2 * (fq * 4 + r))) & 3u;
          if (sel == (uint32_t)f) res[mi][ni][r] = acc[mi][ni][r] + bvf;
        }
      }
    }
  }

  // dense coalesced store with relu. C/D: col=lane&15, row=(lane>>4)*4+reg
#pragma unroll
  for (int ni = 0; ni < 2; ++ni) {
    int col = nBase + wn + ni * 16 + fr;
#pragma unroll
    for (int mi = 0; mi < 4; ++mi) {
      int row0 = mBase + wm + mi * 16 + fq * 4;
#pragma unroll
      for (int r = 0; r < 4; ++r) {
        float o = res[mi][ni][r];
        __builtin_nontemporal_store(o > 0.f ? o : 0.f,
                                    &out[(size_t)(row0 + r) * E_DIM + col]);
      }
    }
  }
}

extern "C" void kernel_launch(void* const* d_in, const int* in_sizes, int n_in,
                              void* d_out, int out_size, void* d_ws, size_t ws_size,
                              hipStream_t stream) {
  const float* x[4]; const float* W[4]; const float* bs[4];
  for (int f = 0; f < 4; ++f) {
    x[f]  = (const float*)d_in[3 * f + 0];
    W[f]  = (const float*)d_in[3 * f + 1];
    bs[f] = (const float*)d_in[3 * f + 2];
  }
  char* ws = (char*)d_ws;
  uint16_t* xb  = (uint16_t*)ws;                               // 32 MB
  uint16_t* Wt  = (uint16_t*)(ws + (size_t)32 * 1024 * 1024);  // 16 MB
  uint32_t* idx2 = (uint32_t*)(ws + (size_t)48 * 1024 * 1024); //  2 MB
  float* out = (float*)d_out;

  prep_kernel<<<dim3(26624), dim3(256), 0, stream>>>(
      x[0], x[1], x[2], x[3], W[0], W[1], W[2], W[3], xb, Wt, idx2);
  gemm_fused<<<dim3(E_DIM / 128, B_DIM / 128), dim3(512), 0, stream>>>(
      xb, Wt, idx2, bs[0], bs[1], bs[2], bs[3], out);
}